// Round 1
// baseline (90.375 us; speedup 1.0000x reference)
//
#include <hip/hip_runtime.h>
#include <hip/hip_bf16.h>

#define B_Q 4096
#define R_T 500
#define D_E 64
#define N_N 100000
#define E_E 3200000

// ---------------------------------------------------------------------------
// slot[n] = min query index b with query_entities[b]==n, else 0x7F7F7F7F
// ---------------------------------------------------------------------------
__global__ __launch_bounds__(256) void k_build_slot(const int* __restrict__ qents,
                                                    int* __restrict__ slot) {
    int b = blockIdx.x * blockDim.x + threadIdx.x;
    if (b < B_Q) atomicMin(&slot[qents[b]], b);
}

// ---------------------------------------------------------------------------
// One pass over all edges:
//   rel_freq[t] += 1 (per-block LDS histogram, then flushed)
//   C[slot[src]][t] += 1 ; if dst!=src: C[slot[dst]][t] += 1
// (matches reference's  +src +dst -self_loop  exactly)
// ---------------------------------------------------------------------------
__global__ __launch_bounds__(256) void k_edge_scatter(const int* __restrict__ ei,
                                                      const int* __restrict__ et,
                                                      const int* __restrict__ slot,
                                                      int* __restrict__ Cm,
                                                      int* __restrict__ rel_freq) {
    __shared__ int hist[R_T];
    for (int i = threadIdx.x; i < R_T; i += blockDim.x) hist[i] = 0;
    __syncthreads();

    int idx    = blockIdx.x * blockDim.x + threadIdx.x;
    int stride = gridDim.x * blockDim.x;
    for (int e = idx; e < E_E; e += stride) {
        int t = et[e];
        atomicAdd(&hist[t], 1);
        int s = ei[e];
        int d = ei[E_E + e];
        int ss = slot[s];
        if (ss < B_Q) atomicAdd(&Cm[(size_t)ss * R_T + t], 1);
        if (d != s) {
            int sd = slot[d];
            if (sd < B_Q) atomicAdd(&Cm[(size_t)sd * R_T + t], 1);
        }
    }
    __syncthreads();
    for (int i = threadIdx.x; i < R_T; i += blockDim.x) {
        int v = hist[i];
        if (v) atomicAdd(&rel_freq[i], v);
    }
}

// ---------------------------------------------------------------------------
// One wave (64 lanes) per query b; 4 waves per block.
//  - ballot-compact nonzero (r,cnt) of C[slot[q]] into LDS (ascending r)
//  - sparse ent_emb accumulation over ~60 RE rows (coalesced 256B loads)
//  - tiny MLP 132->64->32->16->1 via LDS staging
// ---------------------------------------------------------------------------
__global__ __launch_bounds__(256) void k_gate(
    const float* __restrict__ RE,
    const int* __restrict__ qrels, const int* __restrict__ qents,
    const int* __restrict__ slot,  const int* __restrict__ Cm,
    const int* __restrict__ rel_freq,
    const float* __restrict__ W1, const float* __restrict__ b1,
    const float* __restrict__ W2, const float* __restrict__ b2,
    const float* __restrict__ W3, const float* __restrict__ b3,
    const float* __restrict__ W4, const float* __restrict__ b4,
    float* __restrict__ out)
{
    __shared__ int   sIdx[4][512];
    __shared__ float sCnt[4][512];
    __shared__ float sF [4][132];
    __shared__ float sH1[4][64];
    __shared__ float sH2[4][32];
    __shared__ float sG [4][16];

    const int wid  = threadIdx.x >> 6;
    const int lane = threadIdx.x & 63;
    const int b    = blockIdx.x * 4 + wid;   // grid is exactly B/4 blocks

    const int q  = qents[b];
    const int qr = qrels[b];
    const int sl = slot[q];                  // always < B_Q (q was queried)
    const int*   crow = Cm + (size_t)sl * R_T;
    const float* REb  = RE + (size_t)b * (R_T * D_E);

    // query relation embedding (coalesced 256B row)
    float reb = REb[qr * D_E + lane];

    // --- compact nonzero counts (deterministic ascending order) ---
    int nnz = 0, degl = 0;
    for (int base = 0; base < R_T; base += 64) {
        int r = base + lane;
        int c = (r < R_T) ? crow[r] : 0;
        degl += c;
        unsigned long long m = __ballot(c != 0);
        if (c != 0) {
            int pos = nnz + (int)__popcll(m & ((1ull << lane) - 1ull));
            sIdx[wid][pos] = r;
            sCnt[wid][pos] = (float)c;
        }
        nnz += (int)__popcll(m);
    }
    #pragma unroll
    for (int off = 32; off; off >>= 1) degl += __shfl_xor(degl, off, 64);
    __syncthreads();

    // --- sparse count-weighted sum of relation rows ---
    float acc = 0.f;
    #pragma unroll 4
    for (int k = 0; k < nnz; ++k)
        acc += sCnt[wid][k] * REb[sIdx[wid][k] * D_E + lane];

    float tot = (float)degl;
    float ent = (degl > 0) ? (acc / tot) : 0.f;   // /max(tot,1), zero if tot==0

    // --- assemble feats[132] in LDS ---
    sF[wid][lane]      = reb;
    sF[wid][64 + lane] = ent;
    if (lane == 0) {
        const float invE = (float)(1.0 / (double)E_E);
        float rf   = fminf((float)rel_freq[qr] * invE, 1.f);
        float dn   = fminf(tot * invE, 1.f);
        float dens = fminf((float)((double)E_E / ((double)N_N * (double)N_N)), 1.f);
        sF[wid][128] = rf;
        sF[wid][129] = dn;
        sF[wid][130] = rf;
        sF[wid][131] = dens;
    }
    __syncthreads();

    // --- layer 1: 132 -> 64 (lane j computes h1[j]) ---
    float h = b1[lane];
    #pragma unroll 4
    for (int i = 0; i < 2 * D_E + 4; ++i)
        h = fmaf(sF[wid][i], W1[i * D_E + lane], h);
    sH1[wid][lane] = fmaxf(h, 0.f);
    __syncthreads();

    // --- layer 2: 64 -> 32 ---
    if (lane < 32) {
        float s2 = b2[lane];
        #pragma unroll 4
        for (int i = 0; i < D_E; ++i)
            s2 = fmaf(sH1[wid][i], W2[i * 32 + lane], s2);
        sH2[wid][lane] = fmaxf(s2, 0.f);
    }
    __syncthreads();

    // --- layer 3: 32 -> 16 ---
    if (lane < 16) {
        float s3 = b3[lane];
        #pragma unroll
        for (int i = 0; i < 32; ++i)
            s3 = fmaf(sH2[wid][i], W3[i * 16 + lane], s3);
        sG[wid][lane] = fmaxf(s3, 0.f);
    }
    __syncthreads();

    // --- gate: 16 -> 1, sigmoid ---
    if (lane == 0) {
        float s4 = b4[0];
        #pragma unroll
        for (int i = 0; i < 16; ++i)
            s4 = fmaf(sG[wid][i], W4[i], s4);
        out[b] = 1.f / (1.f + expf(-s4));
    }
}

extern "C" void kernel_launch(void* const* d_in, const int* in_sizes, int n_in,
                              void* d_out, int out_size, void* d_ws, size_t ws_size,
                              hipStream_t stream) {
    const float* RE    = (const float*)d_in[0];
    const int*   qrels = (const int*)d_in[1];
    const int*   qents = (const int*)d_in[2];
    const int*   ei    = (const int*)d_in[3];
    const int*   et    = (const int*)d_in[4];
    const float* W1    = (const float*)d_in[5];
    const float* b1    = (const float*)d_in[6];
    const float* W2    = (const float*)d_in[7];
    const float* b2    = (const float*)d_in[8];
    const float* W3    = (const float*)d_in[9];
    const float* b3    = (const float*)d_in[10];
    const float* W4    = (const float*)d_in[11];
    const float* b4    = (const float*)d_in[12];
    float* out = (float*)d_out;

    // workspace layout: C[B*R] | rel_freq[R] | slot[N]   (~8.6 MB)
    int* Cm       = (int*)d_ws;
    int* rel_freq = Cm + (size_t)B_Q * R_T;
    int* slot     = rel_freq + R_T;

    hipMemsetAsync(Cm, 0, ((size_t)B_Q * R_T + R_T) * sizeof(int), stream);
    hipMemsetAsync(slot, 0x7F, (size_t)N_N * sizeof(int), stream);  // 0x7F7F7F7F >= B_Q

    k_build_slot<<<(B_Q + 255) / 256, 256, 0, stream>>>(qents, slot);
    k_edge_scatter<<<512, 256, 0, stream>>>(ei, et, slot, Cm, rel_freq);
    k_gate<<<B_Q / 4, 256, 0, stream>>>(RE, qrels, qents, slot, Cm, rel_freq,
                                        W1, b1, W2, b2, W3, b3, W4, b4, out);
}